// Round 1
// baseline (455.764 us; speedup 1.0000x reference)
//
#include <hip/hip_runtime.h>
#include <math.h>

// ---------------------------------------------------------------------------
// SocialLstm: T=24, N=2048, INPUT_DIM=2, HIDDEN=64, MEDIATE=128, SOCIAL=64,
// OUT_DIM=2, N_SIZE=2, CELL=0.3, T_obs=9, T_pred=19, WIN=9.
//
// Key structural facts exploited:
//  * social-pool coords always come from X[t] (never from predictions) ->
//    match lists precomputable for all 20 steps, independent of recurrence.
//  * Hf = tile(cell_val, 9) -> Hf @ W_soc.T == cell_val @ Wsoc_eff.T with
//    Wsoc_eff[s][k] = sum_{w<9} W_soc[s][w*64+k].
//  * per-step GEMM: g[2048][256] = [r(128)|e(64)|h(64)] @ [W_ih|W_hh].T
// ---------------------------------------------------------------------------

#define N_AG   2048
#define HID    64
#define STEPS  20
#define CAP    12      // max match-list entries per agent (Poisson(~0.3) cell occupancy -> hugely safe)

// ---------------------------------------------------------------------------
// k_init: copy h0/c from inputs, zero output tail frames 20..23, build
// Wsoc_eff (64x64), bc = b_ih + b_hh (256), and the repacked combined weight
// WcP[kb][g][j] = Wc[g][kb*4+j] where Wc = [W_ih | W_hh] (256 x 256).
// ---------------------------------------------------------------------------
__global__ void k_init(const float* __restrict__ h_in, const float* __restrict__ c_in,
                       const float* __restrict__ Wsoc,
                       const float* __restrict__ bih, const float* __restrict__ bhh,
                       const float* __restrict__ Wih, const float* __restrict__ Whh,
                       float* __restrict__ h0, float* __restrict__ cbuf,
                       float* __restrict__ WcP, float* __restrict__ We,
                       float* __restrict__ bc, float* __restrict__ otail)
{
    int idx = blockIdx.x * 256 + threadIdx.x;
    if (idx < 131072) { h0[idx] = h_in[idx]; return; }
    idx -= 131072;
    if (idx < 131072) { cbuf[idx] = c_in[idx]; return; }
    idx -= 131072;
    if (idx < 16384)  { otail[idx] = 0.f; return; }   // frames 20..23 of d_out
    idx -= 16384;
    if (idx < 4096) {
        int s = idx >> 6, k = idx & 63;
        float a = 0.f;
        #pragma unroll
        for (int w = 0; w < 9; w++) a += Wsoc[s * 576 + w * 64 + k];
        We[idx] = a; return;
    }
    idx -= 4096;
    if (idx < 256) { bc[idx] = bih[idx] + bhh[idx]; return; }
    idx -= 256;
    if (idx < 65536) {
        int kb = idx >> 10; int rem = idx & 1023; int g = rem >> 2; int j = rem & 3;
        int k = kb * 4 + j;
        WcP[idx] = (k < 192) ? Wih[g * 192 + k] : Whh[g * 64 + (k - 192)];
        return;
    }
}

// ---------------------------------------------------------------------------
// k_grid: per step t, lt = min(coords) - 1.2 (over ALL agents, masked incl.),
// p = floor((x - lt)/0.3) (exact fp32 op sequence of the reference),
// p *= (int)mask, key = px*65536 + py. Target cell key for agent i is then
// key[i] - 65537 (masked agents get -65537, unmatched forever since keys>=0).
// ---------------------------------------------------------------------------
__global__ void k_grid(const float* __restrict__ X, const float* __restrict__ masks,
                       int* __restrict__ keys)
{
    int t = blockIdx.x;
    int tid = threadIdx.x;
    __shared__ float red[256];
    const float* Xt = X + t * N_AG * 2;

    float mnx = 1e30f, mny = 1e30f;
    for (int i = tid; i < N_AG; i += 256) {
        mnx = fminf(mnx, Xt[2 * i]);
        mny = fminf(mny, Xt[2 * i + 1]);
    }
    red[tid] = mnx; __syncthreads();
    for (int s = 128; s > 0; s >>= 1) { if (tid < s) red[tid] = fminf(red[tid], red[tid + s]); __syncthreads(); }
    float ltx = red[0]; __syncthreads();
    red[tid] = mny; __syncthreads();
    for (int s = 128; s > 0; s >>= 1) { if (tid < s) red[tid] = fminf(red[tid], red[tid + s]); __syncthreads(); }
    float lty = red[0]; __syncthreads();

    ltx -= 1.2f;  // margin = 2*N_SIZE*CELL = 1.2 (f32(1.2) == reference's weak-typed scalar)
    lty -= 1.2f;

    for (int i = tid; i < N_AG; i += 256) {
        float m = masks[t * N_AG + i];
        int px = (int)floorf((Xt[2 * i]     - ltx) / 0.3f);
        int py = (int)floorf((Xt[2 * i + 1] - lty) / 0.3f);
        int im = (int)m;           // mask is exactly 0.0f or 1.0f
        px *= im; py *= im;
        keys[t * N_AG + i] = px * 65536 + py;
    }
}

// ---------------------------------------------------------------------------
// k_match: build sparse match lists. Block (t, chunk of 256 agents): stage all
// 2048 keys in LDS, each thread scans all j for key[j] == key[i]-65537.
// ---------------------------------------------------------------------------
__global__ void k_match(const int* __restrict__ keys, int* __restrict__ mcnt,
                        int* __restrict__ midx)
{
    int t = blockIdx.x >> 3;
    int chunk = blockIdx.x & 7;
    __shared__ int kk[N_AG];
    const int* kt = keys + t * N_AG;
    for (int i = threadIdx.x; i < N_AG; i += 256) kk[i] = kt[i];
    __syncthreads();

    int i = chunk * 256 + threadIdx.x;
    int tkey = kk[i] - 65537;
    int cnt = 0;
    int base = (t * N_AG + i) * CAP;
    const int4* K4 = (const int4*)kk;
    for (int j4 = 0; j4 < N_AG / 4; j4++) {
        int4 v = K4[j4];
        if (v.x == tkey) { if (cnt < CAP) midx[base + cnt] = j4 * 4 + 0; cnt++; }
        if (v.y == tkey) { if (cnt < CAP) midx[base + cnt] = j4 * 4 + 1; cnt++; }
        if (v.z == tkey) { if (cnt < CAP) midx[base + cnt] = j4 * 4 + 2; cnt++; }
        if (v.w == tkey) { if (cnt < CAP) midx[base + cnt] = j4 * 4 + 3; cnt++; }
    }
    if (cnt > CAP) cnt = CAP;
    mcnt[t * N_AG + i] = cnt;
}

// ---------------------------------------------------------------------------
// k_step: one full recurrence step for all 2048 agents.
// 256 blocks x 256 threads, 8 agents per block.
//  phase 1: r = relu(W_in @ pt + b_in)            -> zh[a][0:128]
//  phase 2: cell_val (sparse gather of h_prev), e -> zh[a][128:192]
//  phase 3: h_prev staging                        -> zh[a][192:256]
//  phase 4: g[a][256] = bc + zh[a] . Wc[g]   (thread = gate, 8 agents/thread)
//  phase 5: LSTM elementwise, write h_next / c
//  phase 6: out = (h @ W_out.T + b_out) * mask
// ---------------------------------------------------------------------------
__global__ __launch_bounds__(256) void k_step(
    int t,
    const float* __restrict__ rsrc,      // [N,2] input to the r-MLP (X[t] or out[t-2])
    const float* __restrict__ masks,
    const float* __restrict__ Win, const float* __restrict__ bin,
    const float* __restrict__ bsoc,
    const float* __restrict__ Wout, const float* __restrict__ bout,
    const float* __restrict__ WcP, const float* __restrict__ We,
    const float* __restrict__ bc,
    const int* __restrict__ mcnt, const int* __restrict__ midx,
    const float* __restrict__ hprev, float* __restrict__ hnext,
    float* __restrict__ cbuf, float* __restrict__ out)
{
    __shared__ __align__(16) float zh[8][256];
    __shared__ float gbuf[8][256];
    __shared__ float cvs[8][64];
    __shared__ float hs[8][64];

    const int tid   = threadIdx.x;
    const int ag    = tid >> 5;
    const int lane  = tid & 31;
    const int agent = blockIdx.x * 8 + ag;
    const float mask = masks[t * N_AG + agent];

    // phase 1: r
    {
        float px = rsrc[agent * 2], py = rsrc[agent * 2 + 1];
        #pragma unroll
        for (int u = 0; u < 4; u++) {
            int j = lane + 32 * u;
            zh[ag][j] = fmaxf(Win[2 * j] * px + Win[2 * j + 1] * py + bin[j], 0.f);
        }
    }

    // phase 2a: cell_val gather (sparse; usually cnt == 0)
    int cnt = mcnt[t * N_AG + agent];
    {
        int base = (t * N_AG + agent) * CAP;
        float cv0 = 0.f, cv1 = 0.f;
        for (int n = 0; n < cnt; n++) {
            int j = midx[base + n];
            cv0 += hprev[j * HID + lane];
            cv1 += hprev[j * HID + lane + 32];
        }
        cvs[ag][lane]      = cv0 * mask;
        cvs[ag][lane + 32] = cv1 * mask;
    }

    // phase 3: stage h_prev
    zh[ag][192 + lane]      = hprev[agent * HID + lane];
    zh[ag][192 + lane + 32] = hprev[agent * HID + lane + 32];
    __syncthreads();

    // phase 2b: e = relu(cell_val @ We.T + b_soc)
    {
        bool zerocv = (cnt == 0) || (mask == 0.f);
        #pragma unroll
        for (int v = 0; v < 2; v++) {
            int s = lane + 32 * v;
            float acc = bsoc[s];
            if (!zerocv) {
                for (int k = 0; k < 64; k++) acc += cvs[ag][k] * We[s * 64 + k];
            }
            zh[ag][128 + s] = fmaxf(acc, 0.f);
        }
    }
    __syncthreads();

    // phase 4: main GEMM — thread = gate g, all 8 agents
    {
        const int g = tid;
        float acc[8];
        const float b0 = bc[g];
        #pragma unroll
        for (int a = 0; a < 8; a++) acc[a] = b0;
        const float4* W4 = (const float4*)WcP;
        for (int kb = 0; kb < 64; kb++) {
            float4 w = W4[kb * 256 + g];
            #pragma unroll
            for (int a = 0; a < 8; a++) {
                float4 z = *(const float4*)(&zh[a][kb * 4]);
                acc[a] += w.x * z.x + w.y * z.y + w.z * z.z + w.w * z.w;
            }
        }
        #pragma unroll
        for (int a = 0; a < 8; a++) gbuf[a][g] = acc[a];
    }
    __syncthreads();

    // phase 5: LSTM elementwise
    #pragma unroll
    for (int v = 0; v < 2; v++) {
        int hid = lane + 32 * v;
        float gi = gbuf[ag][hid];
        float gf = gbuf[ag][64 + hid];
        float gg = gbuf[ag][128 + hid];
        float go = gbuf[ag][192 + hid];
        float cp = cbuf[agent * HID + hid];
        float si = 1.f / (1.f + expf(-gi));
        float sf = 1.f / (1.f + expf(-gf));
        float so = 1.f / (1.f + expf(-go));
        float cn = sf * cp + si * tanhf(gg);
        float hn = so * tanhf(cn);
        cbuf[agent * HID + hid]  = cn;
        hnext[agent * HID + hid] = hn;
        hs[ag][hid] = hn;
    }
    __syncthreads();

    // phase 6: out = (h @ W_out.T + b_out) * mask
    if (tid < 16) {
        int a2 = tid >> 1, d = tid & 1;
        int agent2 = blockIdx.x * 8 + a2;
        float m2 = masks[t * N_AG + agent2];
        float acc2 = bout[d];
        for (int k = 0; k < 64; k++) acc2 += hs[a2][k] * Wout[d * 64 + k];
        out[(t * N_AG + agent2) * 2 + d] = acc2 * m2;
    }
}

// ---------------------------------------------------------------------------
extern "C" void kernel_launch(void* const* d_in, const int* in_sizes, int n_in,
                              void* d_out, int out_size, void* d_ws, size_t ws_size,
                              hipStream_t stream)
{
    const float* X     = (const float*)d_in[0];
    const float* masks = (const float*)d_in[1];
    const float* h_in  = (const float*)d_in[2];
    const float* c_in  = (const float*)d_in[3];
    // d_in[4] = Y (unused), d_in[5] = T_obs (=9), d_in[6] = T_pred (=19)
    const float* Win   = (const float*)d_in[7];
    const float* bin   = (const float*)d_in[8];
    const float* Wsoc  = (const float*)d_in[9];
    const float* bsoc  = (const float*)d_in[10];
    const float* Wih   = (const float*)d_in[11];
    const float* Whh   = (const float*)d_in[12];
    const float* bih   = (const float*)d_in[13];
    const float* bhh   = (const float*)d_in[14];
    const float* Wout  = (const float*)d_in[15];
    const float* bout  = (const float*)d_in[16];
    float* out = (float*)d_out;

    // workspace layout
    float* ws  = (float*)d_ws;
    float* h0  = ws;                 // 131072
    float* h1  = h0 + 131072;        // 131072
    float* cb  = h1 + 131072;        // 131072
    float* WcP = cb + 131072;        // 65536
    float* We  = WcP + 65536;        // 4096
    float* bc  = We + 4096;          // 256
    int*   keys = (int*)(bc + 256);  // 20*2048
    int*   mcnt = keys + STEPS * N_AG;            // 20*2048
    int*   midx = mcnt + STEPS * N_AG;            // 20*2048*CAP

    k_init<<<1361, 256, 0, stream>>>(h_in, c_in, Wsoc, bih, bhh, Wih, Whh,
                                     h0, cb, WcP, We, bc, out + 20 * N_AG * 2);
    k_grid<<<STEPS, 256, 0, stream>>>(X, masks, keys);
    k_match<<<STEPS * 8, 256, 0, stream>>>(keys, mcnt, midx);

    for (int t = 0; t < STEPS; t++) {
        // r-input: obs frames (t<=9) use X[t]; frame 10 uses X[10]; t>=11 uses out[t-2]
        const float* rsrc = (t <= 10) ? (X + t * N_AG * 2) : (out + (t - 2) * N_AG * 2);
        float* hp = (t & 1) ? h1 : h0;
        float* hn = (t & 1) ? h0 : h1;
        k_step<<<N_AG / 8, 256, 0, stream>>>(t, rsrc, masks, Win, bin, bsoc, Wout, bout,
                                             WcP, We, bc, mcnt, midx, hp, hn, cb, out);
    }
}

// Round 2
// 417.423 us; speedup vs baseline: 1.0919x; 1.0919x over previous
//
#include <hip/hip_runtime.h>
#include <math.h>

// ---------------------------------------------------------------------------
// SocialLstm: T=24, N=2048, INPUT_DIM=2, HIDDEN=64, MEDIATE=128, SOCIAL=64,
// OUT_DIM=2, N_SIZE=2, CELL=0.3, T_obs=9, T_pred=19, WIN=9.
//
//  * social-pool coords always come from X[t] -> match lists precomputable.
//  * Hf = tile(cell_val,9) -> Hf @ W_soc.T == cell_val @ We.T,
//    We[s][k] = sum_w W_soc[s][w*64+k].
//  * per-step GEMM: g[2048][256] = [r(128)|e(64)|h(64)] @ [W_ih|W_hh].T
//
// R1: O(N) LDS hash match (was 64us O(N^2) scan); k_step 4 agents/block,
//     512 blocks -> 2 blocks/CU for latency hiding.
// ---------------------------------------------------------------------------

#define N_AG   2048
#define HID    64
#define STEPS  20
#define CAP    12

// ---------------------------------------------------------------------------
// k_init: copy h0/c, zero tail frames, Wsoc_eff, bc, repacked combined weight
// WcP[kb][g][j] = Wc[g][kb*4+j], Wc = [W_ih | W_hh] (256x256).
// ---------------------------------------------------------------------------
__global__ void k_init(const float* __restrict__ h_in, const float* __restrict__ c_in,
                       const float* __restrict__ Wsoc,
                       const float* __restrict__ bih, const float* __restrict__ bhh,
                       const float* __restrict__ Wih, const float* __restrict__ Whh,
                       float* __restrict__ h0, float* __restrict__ cbuf,
                       float* __restrict__ WcP, float* __restrict__ We,
                       float* __restrict__ bc, float* __restrict__ otail)
{
    int idx = blockIdx.x * 256 + threadIdx.x;
    if (idx < 131072) { h0[idx] = h_in[idx]; return; }
    idx -= 131072;
    if (idx < 131072) { cbuf[idx] = c_in[idx]; return; }
    idx -= 131072;
    if (idx < 16384)  { otail[idx] = 0.f; return; }   // frames 20..23 of d_out
    idx -= 16384;
    if (idx < 4096) {
        int s = idx >> 6, k = idx & 63;
        float a = 0.f;
        #pragma unroll
        for (int w = 0; w < 9; w++) a += Wsoc[s * 576 + w * 64 + k];
        We[idx] = a; return;
    }
    idx -= 4096;
    if (idx < 256) { bc[idx] = bih[idx] + bhh[idx]; return; }
    idx -= 256;
    if (idx < 65536) {
        int kb = idx >> 10; int rem = idx & 1023; int g = rem >> 2; int j = rem & 3;
        int k = kb * 4 + j;
        WcP[idx] = (k < 192) ? Wih[g * 192 + k] : Whh[g * 64 + (k - 192)];
        return;
    }
}

// ---------------------------------------------------------------------------
// k_gridmatch: one block per step t. min-reduce coords, exact fp32 key calc
// (floor((x-lt)/0.3), p*=mask, key=px*65536+py), then O(N) hash match:
// insert all (key[j], j) into a 2048-bucket LDS chain hash, probe each i for
// target key[i]-65537. Masked agents key=0; probe targets never 0 (p>=4).
// ---------------------------------------------------------------------------
__device__ __forceinline__ int khash(int k) {
    return (int)(((unsigned)k * 2654435761u) >> 21);   // 11-bit bucket
}

__global__ void k_gridmatch(const float* __restrict__ X, const float* __restrict__ masks,
                            int* __restrict__ mcnt, int* __restrict__ midx)
{
    int t = blockIdx.x;
    int tid = threadIdx.x;
    __shared__ float red[256];
    __shared__ int kk[N_AG];
    __shared__ int head[N_AG];
    __shared__ int nxt[N_AG];
    const float* Xt = X + t * N_AG * 2;

    float mnx = 1e30f, mny = 1e30f;
    for (int i = tid; i < N_AG; i += 256) {
        mnx = fminf(mnx, Xt[2 * i]);
        mny = fminf(mny, Xt[2 * i + 1]);
    }
    red[tid] = mnx; __syncthreads();
    for (int s = 128; s > 0; s >>= 1) { if (tid < s) red[tid] = fminf(red[tid], red[tid + s]); __syncthreads(); }
    float ltx = red[0]; __syncthreads();
    red[tid] = mny; __syncthreads();
    for (int s = 128; s > 0; s >>= 1) { if (tid < s) red[tid] = fminf(red[tid], red[tid + s]); __syncthreads(); }
    float lty = red[0]; __syncthreads();

    ltx -= 1.2f;   // margin = 2*N_SIZE*CELL
    lty -= 1.2f;

    for (int i = tid; i < N_AG; i += 256) {
        float m = masks[t * N_AG + i];
        int px = (int)floorf((Xt[2 * i]     - ltx) / 0.3f);
        int py = (int)floorf((Xt[2 * i + 1] - lty) / 0.3f);
        int im = (int)m;
        px *= im; py *= im;
        kk[i] = px * 65536 + py;
        head[i] = -1;
    }
    __syncthreads();

    // insert (LIFO chains; order fixed up by sort below)
    for (int j = tid; j < N_AG; j += 256) {
        int h = khash(kk[j]);
        nxt[j] = atomicExch(&head[h], j);
    }
    __syncthreads();

    // probe
    for (int i = tid; i < N_AG; i += 256) {
        int tkey = kk[i] - 65537;
        int lst[CAP];
        int cnt = 0;
        for (int j = head[khash(tkey)]; j >= 0; j = nxt[j]) {
            if (kk[j] == tkey) { if (cnt < CAP) lst[cnt] = j; cnt++; }
        }
        if (cnt > CAP) cnt = CAP;
        // insertion sort ascending j -> deterministic summation order
        for (int a = 1; a < cnt; a++) {
            int v = lst[a]; int b = a - 1;
            while (b >= 0 && lst[b] > v) { lst[b + 1] = lst[b]; b--; }
            lst[b + 1] = v;
        }
        int base = (t * N_AG + i) * CAP;
        for (int a = 0; a < cnt; a++) midx[base + a] = lst[a];
        mcnt[t * N_AG + i] = cnt;
    }
}

// ---------------------------------------------------------------------------
// k_step: one recurrence step, 4 agents/block x 512 blocks, 256 threads.
// Wave (64 lanes) <-> one agent for phases 1/2/3/5 (broadcast-aligned).
//  phase 1: r = relu(W_in @ pt + b_in)            -> zh[a][0:128]
//  phase 2: cell_val (sparse gather), e           -> zh[a][128:192]
//  phase 3: h_prev staging                        -> zh[a][192:256]
//  phase 4: g[a][256] = bc + zh[a] . Wc[g]   (thread = gate, 4 agents)
//  phase 5: LSTM elementwise -> h_next / c
//  phase 6: out = (h @ W_out.T + b_out) * mask
// ---------------------------------------------------------------------------
__global__ __launch_bounds__(256) void k_step(
    int t,
    const float* __restrict__ rsrc,      // [N,2]: X[t] (t<=10) or out[t-2]
    const float* __restrict__ masks,
    const float* __restrict__ Win, const float* __restrict__ bin,
    const float* __restrict__ bsoc,
    const float* __restrict__ Wout, const float* __restrict__ bout,
    const float* __restrict__ WcP, const float* __restrict__ We,
    const float* __restrict__ bc,
    const int* __restrict__ mcnt, const int* __restrict__ midx,
    const float* __restrict__ hprev, float* __restrict__ hnext,
    float* __restrict__ cbuf, float* __restrict__ out)
{
    __shared__ __align__(16) float zh[4][256];
    __shared__ float gbuf[4][256];
    __shared__ float cvs[4][64];
    __shared__ float hs[4][64];

    const int tid   = threadIdx.x;
    const int ag    = tid >> 6;          // wave index == agent slot
    const int lane  = tid & 63;
    const int agent = blockIdx.x * 4 + ag;
    const float mask = masks[t * N_AG + agent];

    // phase 1: r (128 outputs per agent, 2 per lane)
    {
        float px = rsrc[agent * 2], py = rsrc[agent * 2 + 1];
        #pragma unroll
        for (int u = 0; u < 2; u++) {
            int j = lane + 64 * u;
            zh[ag][j] = fmaxf(Win[2 * j] * px + Win[2 * j + 1] * py + bin[j], 0.f);
        }
    }

    // phase 2a: cell_val gather (sparse; usually cnt == 0)
    int cnt = mcnt[t * N_AG + agent];
    {
        int base = (t * N_AG + agent) * CAP;
        float cv = 0.f;
        for (int n = 0; n < cnt; n++) {
            int j = midx[base + n];
            cv += hprev[j * HID + lane];
        }
        cvs[ag][lane] = cv * mask;
    }

    // phase 3: stage h_prev
    zh[ag][192 + lane] = hprev[agent * HID + lane];
    __syncthreads();

    // phase 2b: e = relu(cell_val @ We.T + b_soc), one output per lane
    {
        float acc = bsoc[lane];
        if (cnt > 0 && mask != 0.f) {
            for (int k = 0; k < 64; k++) acc += cvs[ag][k] * We[lane * 64 + k];
        }
        zh[ag][128 + lane] = fmaxf(acc, 0.f);
    }
    __syncthreads();

    // phase 4: main GEMM — thread = gate g, 4 agents
    {
        const int g = tid;
        float acc[4];
        const float b0 = bc[g];
        #pragma unroll
        for (int a = 0; a < 4; a++) acc[a] = b0;
        const float4* W4 = (const float4*)WcP;
        for (int kb = 0; kb < 64; kb++) {
            float4 w = W4[kb * 256 + g];
            #pragma unroll
            for (int a = 0; a < 4; a++) {
                float4 z = *(const float4*)(&zh[a][kb * 4]);
                acc[a] += w.x * z.x + w.y * z.y + w.z * z.z + w.w * z.w;
            }
        }
        #pragma unroll
        for (int a = 0; a < 4; a++) gbuf[a][g] = acc[a];
    }
    __syncthreads();

    // phase 5: LSTM elementwise (one hid per lane)
    {
        int hid = lane;
        float gi = gbuf[ag][hid];
        float gf = gbuf[ag][64 + hid];
        float gg = gbuf[ag][128 + hid];
        float go = gbuf[ag][192 + hid];
        float cp = cbuf[agent * HID + hid];
        float si = 1.f / (1.f + expf(-gi));
        float sf = 1.f / (1.f + expf(-gf));
        float so = 1.f / (1.f + expf(-go));
        float cn = sf * cp + si * tanhf(gg);
        float hn = so * tanhf(cn);
        cbuf[agent * HID + hid]  = cn;
        hnext[agent * HID + hid] = hn;
        hs[ag][hid] = hn;
    }
    __syncthreads();

    // phase 6: out = (h @ W_out.T + b_out) * mask
    if (tid < 8) {
        int a2 = tid >> 1, d = tid & 1;
        int agent2 = blockIdx.x * 4 + a2;
        float m2 = masks[t * N_AG + agent2];
        float acc2 = bout[d];
        for (int k = 0; k < 64; k++) acc2 += hs[a2][k] * Wout[d * 64 + k];
        out[(t * N_AG + agent2) * 2 + d] = acc2 * m2;
    }
}

// ---------------------------------------------------------------------------
extern "C" void kernel_launch(void* const* d_in, const int* in_sizes, int n_in,
                              void* d_out, int out_size, void* d_ws, size_t ws_size,
                              hipStream_t stream)
{
    const float* X     = (const float*)d_in[0];
    const float* masks = (const float*)d_in[1];
    const float* h_in  = (const float*)d_in[2];
    const float* c_in  = (const float*)d_in[3];
    // d_in[4] = Y (unused), d_in[5] = T_obs (=9), d_in[6] = T_pred (=19)
    const float* Win   = (const float*)d_in[7];
    const float* bin   = (const float*)d_in[8];
    const float* Wsoc  = (const float*)d_in[9];
    const float* bsoc  = (const float*)d_in[10];
    const float* Wih   = (const float*)d_in[11];
    const float* Whh   = (const float*)d_in[12];
    const float* bih   = (const float*)d_in[13];
    const float* bhh   = (const float*)d_in[14];
    const float* Wout  = (const float*)d_in[15];
    const float* bout  = (const float*)d_in[16];
    float* out = (float*)d_out;

    // workspace layout
    float* ws  = (float*)d_ws;
    float* h0  = ws;                 // 131072
    float* h1  = h0 + 131072;        // 131072
    float* cb  = h1 + 131072;        // 131072
    float* WcP = cb + 131072;        // 65536
    float* We  = WcP + 65536;        // 4096
    float* bc  = We + 4096;          // 256
    int*   mcnt = (int*)(bc + 256);               // 20*2048
    int*   midx = mcnt + STEPS * N_AG;            // 20*2048*CAP

    k_init<<<1361, 256, 0, stream>>>(h_in, c_in, Wsoc, bih, bhh, Wih, Whh,
                                     h0, cb, WcP, We, bc, out + 20 * N_AG * 2);
    k_gridmatch<<<STEPS, 256, 0, stream>>>(X, masks, mcnt, midx);

    for (int t = 0; t < STEPS; t++) {
        // r-input: obs frames (t<=9) use X[t]; frame 10 uses X[10]; t>=11 uses out[t-2]
        const float* rsrc = (t <= 10) ? (X + t * N_AG * 2) : (out + (t - 2) * N_AG * 2);
        float* hp = (t & 1) ? h1 : h0;
        float* hn = (t & 1) ? h0 : h1;
        k_step<<<N_AG / 4, 256, 0, stream>>>(t, rsrc, masks, Win, bin, bsoc, Wout, bout,
                                             WcP, We, bc, mcnt, midx, hp, hn, cb, out);
    }
}